// Round 6
// baseline (315.821 us; speedup 1.0000x reference)
//
#include <hip/hip_runtime.h>
#include <hip/hip_bf16.h>
#include <cstdint>

#define N_NODES 50000
#define N_EDGES 1600000
#define DIM 128
#define NREL 8
#define LN_EPS 1e-5f

#define NKEYS (N_NODES * NREL)          // 400000
#define SCAN_CHUNK 1024                 // keys per scan block (256 thr x 4)
#define SCAN_NBLK ((NKEYS + SCAN_CHUNK - 1) / SCAN_CHUNK)  // 391

#define A_STRIDE 136                    // ushorts per LDS A row (128 + 8 pad)
#define B_STRIDE 136                    // ushorts per LDS B row

#define CNT_BLOCKS ((N_EDGES + 1023) / 1024)   // 1563 (4 edges/thread)
#define XB_BLOCKS 6250                  // N_NODES*DIM/4 / 256
#define BT_BLOCKS 576                   // 9*128*128 / 256

typedef unsigned short ushort_t;
typedef short short8 __attribute__((ext_vector_type(8)));
typedef float f32x4 __attribute__((ext_vector_type(4)));
typedef unsigned uintx4 __attribute__((ext_vector_type(4)));

__device__ inline ushort_t f2bf(float f) {
    union { float f; unsigned u; } v; v.f = f;
    unsigned r = (v.u + 0x7FFFu + ((v.u >> 16) & 1u)) >> 16;
    return (ushort_t)r;
}
__device__ inline float bf_lo(unsigned u) {
    union { unsigned u; float f; } v; v.u = u << 16;
    return v.f;
}
__device__ inline float bf_hi(unsigned u) {
    union { unsigned u; float f; } v; v.u = u & 0xffff0000u;
    return v.f;
}

// ---------------------------------------------------------------------------
// Fused prep + count_rank. R16: count section processes 4 edges/thread with
// 4 INDEPENDENT atomicAdds in flight (prep was 70.5 us at VALUBusy 1.7%,
// WRITE 69MB = 19.5 legit + ~50MB atomic RMW traffic: throughput-limited by
// single-outstanding memory-side atomics). Stride-256 within a 1024-edge
// chunk keeps ei/et/krk coalesced.
// ---------------------------------------------------------------------------
__global__ __launch_bounds__(256) void prep_kernel(const float* __restrict__ x,
                                                   ushort_t* __restrict__ xb,
                                                   const float* __restrict__ W_rel,
                                                   const float* __restrict__ W_root,
                                                   ushort_t* __restrict__ Bt,
                                                   const int* __restrict__ ei,
                                                   const int* __restrict__ et,
                                                   unsigned* __restrict__ cnt,
                                                   unsigned* __restrict__ krk) {
    int b = blockIdx.x;
    if (b < CNT_BLOCKS) {
        int e = b * 1024 + threadIdx.x;
        if (b != CNT_BLOCKS - 1) {
            int d0 = ei[N_EDGES + e];
            int d1 = ei[N_EDGES + e + 256];
            int d2 = ei[N_EDGES + e + 512];
            int d3 = ei[N_EDGES + e + 768];
            int t0 = et[e];
            int t1 = et[e + 256];
            int t2 = et[e + 512];
            int t3 = et[e + 768];
            unsigned k0 = (unsigned)d0 * NREL + (unsigned)t0;
            unsigned k1 = (unsigned)d1 * NREL + (unsigned)t1;
            unsigned k2 = (unsigned)d2 * NREL + (unsigned)t2;
            unsigned k3 = (unsigned)d3 * NREL + (unsigned)t3;
            unsigned r0 = atomicAdd(&cnt[k0], 1u);
            unsigned r1 = atomicAdd(&cnt[k1], 1u);
            unsigned r2 = atomicAdd(&cnt[k2], 1u);
            unsigned r3 = atomicAdd(&cnt[k3], 1u);
            krk[e]       = (k0 << 13) | r0;
            krk[e + 256] = (k1 << 13) | r1;
            krk[e + 512] = (k2 << 13) | r2;
            krk[e + 768] = (k3 << 13) | r3;
        } else {
#pragma unroll
            for (int q = 0; q < 4; ++q) {
                int eq = e + q * 256;
                if (eq < N_EDGES) {
                    int dst = ei[N_EDGES + eq];
                    unsigned key = (unsigned)dst * NREL + (unsigned)et[eq];
                    unsigned rank = atomicAdd(&cnt[key], 1u);
                    krk[eq] = (key << 13) | rank;
                }
            }
        }
    } else if (b < CNT_BLOCKS + XB_BLOCKS) {
        int i = (b - CNT_BLOCKS) * 256 + threadIdx.x;   // float4 index
        float4 v = ((const float4*)x)[i];
        unsigned lo = (unsigned)f2bf(v.x) | ((unsigned)f2bf(v.y) << 16);
        unsigned hi = (unsigned)f2bf(v.z) | ((unsigned)f2bf(v.w) << 16);
        ((uint2*)xb)[i] = make_uint2(lo, hi);
    } else if (b < CNT_BLOCKS + XB_BLOCKS + BT_BLOCKS) {
        int i = (b - CNT_BLOCKS - XB_BLOCKS) * 256 + threadIdx.x;
        int r   = i >> 14;
        int rem = i & 16383;
        int n   = rem >> 7;
        int k   = rem & 127;
        const float* W = (r < NREL) ? (W_rel + (size_t)r * DIM * DIM) : W_root;
        Bt[i] = f2bf(W[(size_t)k * DIM + n]);
    } else {
        // zero row at node index N_NODES: 128 bf16 = 32 x uint2
        if (threadIdx.x < 32)
            ((uint2*)(xb + (size_t)N_NODES * DIM))[threadIdx.x] = make_uint2(0u, 0u);
    }
}

// ---------------------------------------------------------------------------
// Block-local exclusive scan: meta[key] = (local_excl_offset, cnt), plus
// per-block sums. Consumers add bsums[key>>10] for the global offset.
// ---------------------------------------------------------------------------
__global__ __launch_bounds__(256) void scan1_kernel(const unsigned* __restrict__ cnt,
                                                    uint2* __restrict__ meta,
                                                    unsigned* __restrict__ bsums) {
    __shared__ unsigned lds[256];
    int tid = threadIdx.x;
    int i0  = blockIdx.x * SCAN_CHUNK + tid * 4;
    unsigned v[4], incl[4];
    unsigned s = 0;
#pragma unroll
    for (int j = 0; j < 4; ++j) {
        v[j] = (i0 + j < NKEYS) ? cnt[i0 + j] : 0u;
        s += v[j];
        incl[j] = s;
    }
    lds[tid] = s;
    __syncthreads();
    for (int off = 1; off < 256; off <<= 1) {
        unsigned a = (tid >= off) ? lds[tid - off] : 0u;
        __syncthreads();
        lds[tid] += a;
        __syncthreads();
    }
    unsigned base = lds[tid] - s;
#pragma unroll
    for (int j = 0; j < 4; ++j) {
        if (i0 + j < NKEYS) meta[i0 + j] = make_uint2(base + incl[j] - v[j], v[j]);
    }
    if (tid == 255) bsums[blockIdx.x] = lds[255];
}

__global__ __launch_bounds__(512) void scan2_kernel(unsigned* __restrict__ bsums) {
    __shared__ unsigned lds[512];
    int tid = threadIdx.x;
    unsigned v = (tid < SCAN_NBLK) ? bsums[tid] : 0u;
    lds[tid] = v;
    __syncthreads();
    for (int off = 1; off < 512; off <<= 1) {
        unsigned a = (tid >= off) ? lds[tid - off] : 0u;
        __syncthreads();
        lds[tid] += a;
        __syncthreads();
    }
    if (tid < SCAN_NBLK) bsums[tid] = lds[tid] - v;
}

// ---------------------------------------------------------------------------
// Atomic-free counting-sort fill. R16: 4 edges/thread, 4 independent
// krk->meta->store chains in flight (same MLP mechanism as the count fix).
// ---------------------------------------------------------------------------
__global__ __launch_bounds__(256) void fill_kernel(const int* __restrict__ ei,
                                                   const unsigned* __restrict__ krk,
                                                   const uint2* __restrict__ meta,
                                                   const unsigned* __restrict__ bsums,
                                                   int* __restrict__ sorted_src) {
    int b = blockIdx.x;
    int e = b * 1024 + threadIdx.x;
#pragma unroll
    for (int q = 0; q < 4; ++q) {
        int eq = e + q * 256;
        if (eq < N_EDGES) {
            unsigned kr   = krk[eq];
            unsigned key  = kr >> 13;
            unsigned rank = kr & 8191u;
            unsigned p = meta[key].x + bsums[key >> 10] + rank;
            sorted_src[p] = ei[eq];
        }
    }
}

// ---------------------------------------------------------------------------
// R15 aggregate (2-chain, measured ~69 us, occ ~71%): each half-wave owns two
// adjacent buckets; zero-row padding keeps the fused inner loop mask-free.
// In the cr==NREL path both meta entries come from ONE aligned 16B load and
// share one bsums entry.
// ---------------------------------------------------------------------------
__global__ __launch_bounds__(256) void aggregate_kernel(const uint2* __restrict__ meta,
                                                        const unsigned* __restrict__ bsums,
                                                        const int* __restrict__ sorted_src,
                                                        const ushort_t* __restrict__ xb,
                                                        ushort_t* __restrict__ h,
                                                        int r0, int cr) {
    int hw = threadIdx.x >> 5;                      // half-wave id 0..7
    int sl = threadIdx.x & 31;                      // lane covers 4 feats
    int g0 = blockIdx.x * 16 + hw * 2;              // first bucket
    int g1 = g0 + 1;
    int total = N_NODES * cr;
    if (g0 >= total) return;

    unsigned st0, mc0, st1 = 0u, mc1 = 0u;
    if (cr == NREL) {
        uint4 mm = *(const uint4*)&meta[(unsigned)g0];
        unsigned bs = bsums[(unsigned)g0 >> 10];
        st0 = mm.x + bs; mc0 = mm.y;
        st1 = mm.z + bs; mc1 = mm.w;
    } else {
        int n0 = g0 / cr, rl0 = g0 - n0 * cr;
        unsigned key0 = (unsigned)n0 * NREL + (unsigned)(r0 + rl0);
        uint2 md0 = meta[key0];
        st0 = md0.x + bsums[key0 >> 10];
        mc0 = md0.y;
        if (g1 < total) {
            int n1 = g1 / cr, rl1 = g1 - n1 * cr;
            unsigned key1 = (unsigned)n1 * NREL + (unsigned)(r0 + rl1);
            uint2 md1 = meta[key1];
            st1 = md1.x + bsums[key1 >> 10];
            mc1 = md1.y;
        }
    }

    float a00 = 0.f, a01 = 0.f, a02 = 0.f, a03 = 0.f;
    float a10 = 0.f, a11 = 0.f, a12 = 0.f, a13 = 0.f;
    const char* xbase = (const char*)xb;
    unsigned slb = (unsigned)sl << 3;               // byte offset within row

    unsigned c0 = 0, c1 = 0;
    while (c0 < mc0 || c1 < mc1) {
        int sv0 = (c0 + (unsigned)sl < mc0) ? sorted_src[st0 + c0 + sl] : N_NODES;
        int sv1 = (c1 + (unsigned)sl < mc1) ? sorted_src[st1 + c1 + sl] : N_NODES;
        unsigned rem0 = (c0 < mc0) ? ((mc0 - c0 > 32u) ? 32u : (mc0 - c0)) : 0u;
        unsigned rem1 = (c1 < mc1) ? ((mc1 - c1 > 32u) ? 32u : (mc1 - c1)) : 0u;
        unsigned rm = rem0 > rem1 ? rem0 : rem1;
        for (unsigned j = 0; j < rm; j += 4) {
            int s00 = __shfl(sv0, (int)j,     32);
            int s01 = __shfl(sv0, (int)j + 1, 32);
            int s02 = __shfl(sv0, (int)j + 2, 32);
            int s03 = __shfl(sv0, (int)j + 3, 32);
            int s10 = __shfl(sv1, (int)j,     32);
            int s11 = __shfl(sv1, (int)j + 1, 32);
            int s12 = __shfl(sv1, (int)j + 2, 32);
            int s13 = __shfl(sv1, (int)j + 3, 32);
            uint2 d00 = *(const uint2*)(xbase + ((((unsigned)s00) << 8) | slb));
            uint2 d01 = *(const uint2*)(xbase + ((((unsigned)s01) << 8) | slb));
            uint2 d02 = *(const uint2*)(xbase + ((((unsigned)s02) << 8) | slb));
            uint2 d03 = *(const uint2*)(xbase + ((((unsigned)s03) << 8) | slb));
            uint2 d10 = *(const uint2*)(xbase + ((((unsigned)s10) << 8) | slb));
            uint2 d11 = *(const uint2*)(xbase + ((((unsigned)s11) << 8) | slb));
            uint2 d12 = *(const uint2*)(xbase + ((((unsigned)s12) << 8) | slb));
            uint2 d13 = *(const uint2*)(xbase + ((((unsigned)s13) << 8) | slb));
            a00 += (bf_lo(d00.x) + bf_lo(d01.x)) + (bf_lo(d02.x) + bf_lo(d03.x));
            a01 += (bf_hi(d00.x) + bf_hi(d01.x)) + (bf_hi(d02.x) + bf_hi(d03.x));
            a02 += (bf_lo(d00.y) + bf_lo(d01.y)) + (bf_lo(d02.y) + bf_lo(d03.y));
            a03 += (bf_hi(d00.y) + bf_hi(d01.y)) + (bf_hi(d02.y) + bf_hi(d03.y));
            a10 += (bf_lo(d10.x) + bf_lo(d11.x)) + (bf_lo(d12.x) + bf_lo(d13.x));
            a11 += (bf_hi(d10.x) + bf_hi(d11.x)) + (bf_hi(d12.x) + bf_hi(d13.x));
            a12 += (bf_lo(d10.y) + bf_lo(d11.y)) + (bf_lo(d12.y) + bf_lo(d13.y));
            a13 += (bf_hi(d10.y) + bf_hi(d11.y)) + (bf_hi(d12.y) + bf_hi(d13.y));
        }
        c0 += rem0;
        c1 += rem1;
    }

    float inv0 = 1.0f / fmaxf((float)mc0, 1.0f);
    unsigned lo0 = (unsigned)f2bf(a00 * inv0) | ((unsigned)f2bf(a01 * inv0) << 16);
    unsigned hi0 = (unsigned)f2bf(a02 * inv0) | ((unsigned)f2bf(a03 * inv0) << 16);
    ((uint2*)(h + (size_t)g0 * DIM))[sl] = make_uint2(lo0, hi0);
    if (g1 < total) {
        float inv1 = 1.0f / fmaxf((float)mc1, 1.0f);
        unsigned lo1 = (unsigned)f2bf(a10 * inv1) | ((unsigned)f2bf(a11 * inv1) << 16);
        unsigned hi1 = (unsigned)f2bf(a12 * inv1) | ((unsigned)f2bf(a13 * inv1) << 16);
        ((uint2*)(h + (size_t)g1 * DIM))[sl] = make_uint2(lo1, hi1);
    }
}

// ---------------------------------------------------------------------------
// LDS-staged MFMA GEMM + optional fused bias+LN+ReLU.  [R1 known-good form:
// both A and B staged in LDS — R2's B-from-global put an L2 hit on the MFMA
// critical path (MfmaUtil 3.5%, 162 us) and the grid (391 blocks / 256 CU)
// caps occupancy regardless of LDS, so Bs staging costs nothing.]
// ---------------------------------------------------------------------------
__global__ __launch_bounds__(512) void gemm_ln_kernel(const ushort_t* __restrict__ h,
                                                      int cr, int r0,
                                                      const ushort_t* __restrict__ xb,
                                                      const ushort_t* __restrict__ Bt,
                                                      int include_root,
                                                      const float* __restrict__ bias,
                                                      const float* __restrict__ gamma,
                                                      const float* __restrict__ beta,
                                                      float* __restrict__ out,
                                                      int accumulate, int do_ln) {
    __shared__ __align__(16) ushort_t As[128 * A_STRIDE];   // 34.8 KB
    __shared__ __align__(16) ushort_t Bs[128 * B_STRIDE];   // 34.8 KB

    int tid  = threadIdx.x;
    int w    = tid >> 6;          // 0..7
    int lane = tid & 63;
    int m    = lane & 15;
    int quad = lane >> 4;
    int n0   = blockIdx.x * 128;

    f32x4 acc[8];
#pragma unroll
    for (int j = 0; j < 8; ++j) acc[j] = (f32x4){0.f, 0.f, 0.f, 0.f};

    int nrel = cr + include_root;
    for (int rr = 0; rr < nrel; ++rr) {
        int rel = (rr < cr) ? (r0 + rr) : NREL;

        // ---- stage B: 2048 x 16B chunks, 4 per thread (batched) ----
#pragma unroll
        for (int p = 0; p < 4; ++p) {
            int c = tid + 512 * p;
            int row = c >> 4, ch = c & 15;
            uintx4 v = *(const uintx4*)(Bt + ((size_t)rel * DIM + row) * DIM + ch * 8);
            *(uintx4*)&Bs[row * B_STRIDE + ch * 8] = v;
        }
        // ---- stage A: 2048 x 16B chunks (128 rows), 4 per thread ----
#pragma unroll
        for (int p = 0; p < 4; ++p) {
            int c = tid + 512 * p;
            int row = c >> 4, ch = c & 15;
            uintx4 v = (uintx4){0u, 0u, 0u, 0u};
            int node = n0 + row;
            if (node < N_NODES) {
                const ushort_t* src = (rr < cr)
                    ? (h + ((size_t)node * cr + rr) * DIM)
                    : (xb + (size_t)node * DIM);
                v = *(const uintx4*)(src + ch * 8);
            }
            *(uintx4*)&As[row * A_STRIDE + ch * 8] = v;
        }
        __syncthreads();

        // ---- 32 MFMA per wave ----
#pragma unroll
        for (int t = 0; t < 4; ++t) {
            short8 af = *(const short8*)&As[(w * 16 + m) * A_STRIDE + t * 32 + quad * 8];
#pragma unroll
            for (int j = 0; j < 8; ++j) {
                short8 bf = *(const short8*)&Bs[(j * 16 + m) * B_STRIDE + t * 32 + quad * 8];
                acc[j] = __builtin_amdgcn_mfma_f32_16x16x32_bf16(af, bf, acc[j], 0, 0, 0);
            }
        }
        __syncthreads();
    }

    // ---- epilogue ----
    if (do_ln) {
        float bj[8], gj[8], btj[8];
#pragma unroll
        for (int j = 0; j < 8; ++j) {
            bj[j]  = bias[j * 16 + m];
            gj[j]  = gamma[j * 16 + m];
            btj[j] = beta[j * 16 + m];
        }
#pragma unroll
        for (int i = 0; i < 4; ++i) {
            float s = 0.f, sq = 0.f;
#pragma unroll
            for (int j = 0; j < 8; ++j) {
                float v = acc[j][i] + bj[j];
                s  += v;
                sq += v * v;
            }
#pragma unroll
            for (int off = 1; off < 16; off <<= 1) {
                s  += __shfl_xor(s, off, 64);
                sq += __shfl_xor(sq, off, 64);
            }
            float mean = s * (1.0f / DIM);
            float var  = sq * (1.0f / DIM) - mean * mean;
            float rstd = rsqrtf(var + LN_EPS);
            int node = n0 + w * 16 + quad * 4 + i;
            if (node < N_NODES) {
#pragma unroll
                for (int j = 0; j < 8; ++j) {
                    float v = acc[j][i] + bj[j];
                    v = (v - mean) * rstd * gj[j] + btj[j];
                    out[(size_t)node * DIM + j * 16 + m] = fmaxf(v, 0.f);
                }
            }
        }
    } else {
#pragma unroll
        for (int i = 0; i < 4; ++i) {
            int node = n0 + w * 16 + quad * 4 + i;
            if (node < N_NODES) {
#pragma unroll
                for (int j = 0; j < 8; ++j) {
                    size_t o = (size_t)node * DIM + j * 16 + m;
                    float v = acc[j][i];
                    if (accumulate) v += out[o];
                    out[o] = v;
                }
            }
        }
    }
}

// ---------------------------------------------------------------------------
// Standalone bias + LayerNorm + ReLU (fallback for chunked path).
// ---------------------------------------------------------------------------
__global__ __launch_bounds__(256) void ln_kernel(float* __restrict__ out,
                                                 const float* __restrict__ bias,
                                                 const float* __restrict__ gamma,
                                                 const float* __restrict__ beta) {
    int row  = blockIdx.x * 4 + (threadIdx.x >> 6);
    int lane = threadIdx.x & 63;
    if (row >= N_NODES) return;
    float2 v = *(float2*)(out + (size_t)row * DIM + lane * 2);
    float2 bi = *(const float2*)(bias + lane * 2);
    v.x += bi.x;
    v.y += bi.y;
    float s  = v.x + v.y;
    float sq = v.x * v.x + v.y * v.y;
#pragma unroll
    for (int off = 32; off > 0; off >>= 1) {
        s  += __shfl_xor(s, off, 64);
        sq += __shfl_xor(sq, off, 64);
    }
    float mean = s * (1.0f / DIM);
    float var  = sq * (1.0f / DIM) - mean * mean;
    float rstd = rsqrtf(var + LN_EPS);
    float2 g = *(const float2*)(gamma + lane * 2);
    float2 b = *(const float2*)(beta + lane * 2);
    v.x = fmaxf((v.x - mean) * rstd * g.x + b.x, 0.f);
    v.y = fmaxf((v.y - mean) * rstd * g.y + b.y, 0.f);
    *(float2*)(out + (size_t)row * DIM + lane * 2) = v;
}

// ---------------------------------------------------------------------------
extern "C" void kernel_launch(void* const* d_in, const int* in_sizes, int n_in,
                              void* d_out, int out_size, void* d_ws, size_t ws_size,
                              hipStream_t stream) {
    const float* x      = (const float*)d_in[0];
    const int*   ei     = (const int*)d_in[1];
    const int*   et     = (const int*)d_in[2];
    const float* W_rel  = (const float*)d_in[4];
    const float* W_root = (const float*)d_in[5];
    const float* bias   = (const float*)d_in[6];
    const float* gamma  = (const float*)d_in[7];
    const float* beta   = (const float*)d_in[8];
    float*       out    = (float*)d_out;

    // ---- workspace layout ----
    char* ws = (char*)d_ws;
    size_t off = 0;
    auto alloc = [&](size_t bytes) { char* p = ws + off; off = (off + bytes + 255) & ~(size_t)255; return p; };
    unsigned* cnt        = (unsigned*)alloc((size_t)NKEYS * 4);
    uint2*    meta       = (uint2*)alloc((size_t)NKEYS * 8);
    unsigned* bsums      = (unsigned*)alloc((size_t)SCAN_NBLK * 4);
    unsigned* krk        = (unsigned*)alloc((size_t)N_EDGES * 4);
    int*      sorted_src = (int*)alloc((size_t)N_EDGES * 4);
    ushort_t* Bt         = (ushort_t*)alloc((size_t)9 * DIM * DIM * 2);
    ushort_t* xb         = (ushort_t*)alloc((size_t)(N_NODES + 1) * DIM * 2);  // +1 zero row
    size_t fixedOff = off;
    ushort_t* h = (ushort_t*)(ws + fixedOff);
    size_t availB = ws_size > fixedOff ? ws_size - fixedOff : 0;
    size_t perRel = (size_t)N_NODES * DIM * 2;   // 12.8 MB per relation (bf16)
    int chunkR = (int)(availB / perRel);
    if (chunkR > NREL) chunkR = NREL;
    if (chunkR < 1)    chunkR = 1;

    // ---- build counting sort (count fused into prep; no fill atomic) ----
    hipMemsetAsync(cnt, 0, (size_t)NKEYS * 4, stream);
    prep_kernel<<<CNT_BLOCKS + XB_BLOCKS + BT_BLOCKS + 1, 256, 0, stream>>>(
        x, xb, W_rel, W_root, Bt, ei, et, cnt, krk);
    scan1_kernel<<<SCAN_NBLK, 256, 0, stream>>>(cnt, meta, bsums);
    scan2_kernel<<<1, 512, 0, stream>>>(bsums);
    fill_kernel<<<CNT_BLOCKS, 256, 0, stream>>>(ei, krk, meta, bsums, sorted_src);

    int gemmGrid = (N_NODES + 127) / 128;   // 391 blocks

    if (chunkR >= NREL) {
        int nbuck = N_NODES * NREL;
        aggregate_kernel<<<(nbuck + 15) / 16, 256, 0, stream>>>(meta, bsums, sorted_src,
                                                                xb, h, 0, NREL);
        gemm_ln_kernel<<<gemmGrid, 512, 0, stream>>>(h, NREL, 0, xb, Bt, 1,
                                                     bias, gamma, beta, out, 0, 1);
    } else {
        for (int r0 = 0; r0 < NREL; r0 += chunkR) {
            int cr = (NREL - r0 < chunkR) ? (NREL - r0) : chunkR;
            int nbuck = N_NODES * cr;
            aggregate_kernel<<<(nbuck + 15) / 16, 256, 0, stream>>>(meta, bsums, sorted_src,
                                                                    xb, h, r0, cr);
            int include_root = (r0 + cr == NREL) ? 1 : 0;
            gemm_ln_kernel<<<gemmGrid, 512, 0, stream>>>(h, cr, r0, xb, Bt, include_root,
                                                         bias, gamma, beta, out,
                                                         r0 > 0 ? 1 : 0, 0);
        }
        ln_kernel<<<(N_NODES + 3) / 4, 256, 0, stream>>>(out, bias, gamma, beta);
    }
}

// Round 7
// 255.052 us; speedup vs baseline: 1.2383x; 1.2383x over previous
//
#include <hip/hip_runtime.h>
#include <hip/hip_bf16.h>
#include <cstdint>

#define N_NODES 50000
#define N_EDGES 1600000
#define DIM 128
#define NREL 8
#define LN_EPS 1e-5f

#define NKEYS (N_NODES * NREL)          // 400000
#define PA_BLOCKS ((N_EDGES + 1023) / 1024)   // 1563 (1024 edges/block)
#define NBIN ((NKEYS + 1023) / 1024)    // 391 coarse bins (key>>10)
#define BH_STRIDE 1600                  // padded blocks-per-bin row stride

#define A_STRIDE 136                    // ushorts per LDS A row (128 + 8 pad)
#define B_STRIDE 136                    // ushorts per LDS B row

#define XB_BLOCKS 6250                  // N_NODES*DIM/4 / 256
#define BT_BLOCKS 576                   // 9*128*128 / 256

typedef unsigned short ushort_t;
typedef short short8 __attribute__((ext_vector_type(8)));
typedef float f32x4 __attribute__((ext_vector_type(4)));
typedef unsigned uintx4 __attribute__((ext_vector_type(4)));

__device__ inline ushort_t f2bf(float f) {
    union { float f; unsigned u; } v; v.f = f;
    unsigned r = (v.u + 0x7FFFu + ((v.u >> 16) & 1u)) >> 16;
    return (ushort_t)r;
}
__device__ inline float bf_lo(unsigned u) {
    union { unsigned u; float f; } v; v.u = u << 16;
    return v.f;
}
__device__ inline float bf_hi(unsigned u) {
    union { unsigned u; float f; } v; v.u = u & 0xffff0000u;
    return v.f;
}

// ---------------------------------------------------------------------------
// Fused prep + Pass A. R17: the 1.6M device-scope atomicAdds were the wall
// (R16: 4-deep atomic pipelining gave ZERO speedup -> memory-side RMW service
// rate ~23G/s saturated). Replaced by a two-level LDS counting sort with no
// global atomics. Pass A: per-1024-edge block LDS histogram over 391 coarse
// bins (key>>10), written to block_hist[bin][block].
// ---------------------------------------------------------------------------
__global__ __launch_bounds__(256) void prep_kernel(const float* __restrict__ x,
                                                   ushort_t* __restrict__ xb,
                                                   const float* __restrict__ W_rel,
                                                   const float* __restrict__ W_root,
                                                   ushort_t* __restrict__ Bt,
                                                   const int* __restrict__ ei,
                                                   const int* __restrict__ et,
                                                   unsigned* __restrict__ block_hist) {
    int b = blockIdx.x;
    int tid = threadIdx.x;
    if (b < PA_BLOCKS) {
        __shared__ unsigned hist[NBIN];
        for (int i = tid; i < NBIN; i += 256) hist[i] = 0u;
        __syncthreads();
        int e = b * 1024 + tid;
#pragma unroll
        for (int q = 0; q < 4; ++q) {
            int eq = e + q * 256;
            if (eq < N_EDGES) {
                int dst = ei[N_EDGES + eq];
                unsigned key = (unsigned)dst * NREL + (unsigned)et[eq];
                atomicAdd(&hist[key >> 10], 1u);
            }
        }
        __syncthreads();
        for (int i = tid; i < NBIN; i += 256)
            block_hist[(size_t)i * BH_STRIDE + b] = hist[i];
    } else if (b < PA_BLOCKS + XB_BLOCKS) {
        int i = (b - PA_BLOCKS) * 256 + tid;              // float4 index
        float4 v = ((const float4*)x)[i];
        unsigned lo = (unsigned)f2bf(v.x) | ((unsigned)f2bf(v.y) << 16);
        unsigned hi = (unsigned)f2bf(v.z) | ((unsigned)f2bf(v.w) << 16);
        ((uint2*)xb)[i] = make_uint2(lo, hi);
    } else if (b < PA_BLOCKS + XB_BLOCKS + BT_BLOCKS) {
        int i = (b - PA_BLOCKS - XB_BLOCKS) * 256 + tid;
        int r   = i >> 14;
        int rem = i & 16383;
        int n   = rem >> 7;
        int k   = rem & 127;
        const float* W = (r < NREL) ? (W_rel + (size_t)r * DIM * DIM) : W_root;
        Bt[i] = f2bf(W[(size_t)k * DIM + n]);
    } else {
        // zero row at node index N_NODES: 128 bf16 = 32 x uint2
        if (tid < 32)
            ((uint2*)(xb + (size_t)N_NODES * DIM))[tid] = make_uint2(0u, 0u);
    }
}

// ---------------------------------------------------------------------------
// Pass A2: per coarse bin, exclusive-scan its 1563 per-block counts in place;
// bin total to bin_tot. One block per bin.
// ---------------------------------------------------------------------------
__global__ __launch_bounds__(256) void scanA2_kernel(unsigned* __restrict__ bh,
                                                     unsigned* __restrict__ bin_tot) {
    __shared__ unsigned lds[256];
    int k = blockIdx.x;
    int tid = threadIdx.x;
    unsigned* row = bh + (size_t)k * BH_STRIDE;
    int base = tid * 7;                               // 7*256 = 1792 >= 1563
    unsigned v[7];
    unsigned s = 0;
#pragma unroll
    for (int j = 0; j < 7; ++j) {
        int i = base + j;
        v[j] = (i < PA_BLOCKS) ? row[i] : 0u;
        s += v[j];
    }
    lds[tid] = s;
    __syncthreads();
    for (int off = 1; off < 256; off <<= 1) {
        unsigned a = (tid >= off) ? lds[tid - off] : 0u;
        __syncthreads();
        lds[tid] += a;
        __syncthreads();
    }
    unsigned ex = lds[tid] - s;
#pragma unroll
    for (int j = 0; j < 7; ++j) {
        int i = base + j;
        if (i < PA_BLOCKS) {
            unsigned t = v[j];
            row[i] = ex;
            ex += t;
        }
    }
    if (tid == 255) bin_tot[k] = lds[255];
}

// ---------------------------------------------------------------------------
// Pass A3: exclusive scan of the 391 bin totals -> absolute bin bases.
// ---------------------------------------------------------------------------
__global__ __launch_bounds__(512) void scanA3_kernel(const unsigned* __restrict__ bin_tot,
                                                     unsigned* __restrict__ bin_base) {
    __shared__ unsigned lds[512];
    int tid = threadIdx.x;
    unsigned v = (tid < NBIN) ? bin_tot[tid] : 0u;
    lds[tid] = v;
    __syncthreads();
    for (int off = 1; off < 512; off <<= 1) {
        unsigned a = (tid >= off) ? lds[tid - off] : 0u;
        __syncthreads();
        lds[tid] += a;
        __syncthreads();
    }
    if (tid < NBIN) bin_base[tid] = lds[tid] - v;
}

// ---------------------------------------------------------------------------
// Pass B: scatter edges into coarse-bin-contiguous records. Per-block LDS
// cursors (col = bin_base + this block's scanned offset); local rank via LDS
// atomic. Record packs (src << 10) | (key & 1023) -> 4B. Plain stores only.
// ---------------------------------------------------------------------------
__global__ __launch_bounds__(256) void passB_kernel(const int* __restrict__ ei,
                                                    const int* __restrict__ et,
                                                    const unsigned* __restrict__ bh,
                                                    const unsigned* __restrict__ bin_base,
                                                    unsigned* __restrict__ rec) {
    __shared__ unsigned col[NBIN];
    __shared__ unsigned rk[NBIN];
    int b = blockIdx.x;
    int tid = threadIdx.x;
    for (int i = tid; i < NBIN; i += 256) {
        col[i] = bin_base[i] + bh[(size_t)i * BH_STRIDE + b];
        rk[i]  = 0u;
    }
    __syncthreads();
    int e = b * 1024 + tid;
#pragma unroll
    for (int q = 0; q < 4; ++q) {
        int eq = e + q * 256;
        if (eq < N_EDGES) {
            int src = ei[eq];
            int dst = ei[N_EDGES + eq];
            unsigned key = (unsigned)dst * NREL + (unsigned)et[eq];
            unsigned bin = key >> 10;
            unsigned r = atomicAdd(&rk[bin], 1u);
            rec[col[bin] + r] = ((unsigned)src << 10) | (key & 1023u);
        }
    }
}

// ---------------------------------------------------------------------------
// Pass C: per coarse bin fine counting sort (1024 keys). LDS count -> LDS
// scan -> meta (ABSOLUTE starts; bsums eliminated) -> LDS-cursor scatter of
// sorted_src. All global accesses coalesced or bin-local.
// ---------------------------------------------------------------------------
__global__ __launch_bounds__(256) void passC_kernel(const unsigned* __restrict__ rec,
                                                    const unsigned* __restrict__ bin_base,
                                                    const unsigned* __restrict__ bin_tot,
                                                    uint2* __restrict__ meta,
                                                    int* __restrict__ sorted_src) {
    __shared__ unsigned cnt[1024];     // counts, then cursors
    __shared__ unsigned lds[256];
    int k = blockIdx.x;
    int tid = threadIdx.x;
    unsigned base = bin_base[k];
    unsigned tot  = bin_tot[k];
    for (int i = tid; i < 1024; i += 256) cnt[i] = 0u;
    __syncthreads();
    for (unsigned i = tid; i < tot; i += 256) {
        unsigned r = rec[base + i];
        atomicAdd(&cnt[r & 1023u], 1u);
    }
    __syncthreads();
    // scan 1024 counts: thread owns cnt[4t..4t+4)
    unsigned v[4], incl[4], s = 0;
#pragma unroll
    for (int j = 0; j < 4; ++j) {
        v[j] = cnt[tid * 4 + j];
        s += v[j];
        incl[j] = s;
    }
    lds[tid] = s;
    __syncthreads();
    for (int off = 1; off < 256; off <<= 1) {
        unsigned a = (tid >= off) ? lds[tid - off] : 0u;
        __syncthreads();
        lds[tid] += a;
        __syncthreads();
    }
    unsigned bs = lds[tid] - s;
    unsigned key0 = (unsigned)k * 1024 + tid * 4;
#pragma unroll
    for (int j = 0; j < 4; ++j) {
        unsigned ex = bs + incl[j] - v[j];
        if (key0 + j < NKEYS) meta[key0 + j] = make_uint2(base + ex, v[j]);
    }
    __syncthreads();                    // meta writes done reading nothing; cnt rewrite next
#pragma unroll
    for (int j = 0; j < 4; ++j) cnt[tid * 4 + j] = bs + incl[j] - v[j];   // cursors
    __syncthreads();
    for (unsigned i = tid; i < tot; i += 256) {
        unsigned r = rec[base + i];
        unsigned q = r & 1023u;
        unsigned p = atomicAdd(&cnt[q], 1u);
        sorted_src[base + p] = (int)(r >> 10);
    }
}

// ---------------------------------------------------------------------------
// R15 aggregate (2-chain, measured ~69 us, occ ~71%); meta.x is now ABSOLUTE
// (bsums gone). cr==NREL path: adjacent-pair meta via one aligned 16B load.
// ---------------------------------------------------------------------------
__global__ __launch_bounds__(256) void aggregate_kernel(const uint2* __restrict__ meta,
                                                        const int* __restrict__ sorted_src,
                                                        const ushort_t* __restrict__ xb,
                                                        ushort_t* __restrict__ h,
                                                        int r0, int cr) {
    int hw = threadIdx.x >> 5;                      // half-wave id 0..7
    int sl = threadIdx.x & 31;                      // lane covers 4 feats
    int g0 = blockIdx.x * 16 + hw * 2;              // first bucket
    int g1 = g0 + 1;
    int total = N_NODES * cr;
    if (g0 >= total) return;

    unsigned st0, mc0, st1 = 0u, mc1 = 0u;
    if (cr == NREL) {
        uint4 mm = *(const uint4*)&meta[(unsigned)g0];
        st0 = mm.x; mc0 = mm.y;
        st1 = mm.z; mc1 = mm.w;
    } else {
        int n0 = g0 / cr, rl0 = g0 - n0 * cr;
        unsigned key0 = (unsigned)n0 * NREL + (unsigned)(r0 + rl0);
        uint2 md0 = meta[key0];
        st0 = md0.x; mc0 = md0.y;
        if (g1 < total) {
            int n1 = g1 / cr, rl1 = g1 - n1 * cr;
            unsigned key1 = (unsigned)n1 * NREL + (unsigned)(r0 + rl1);
            uint2 md1 = meta[key1];
            st1 = md1.x; mc1 = md1.y;
        }
    }

    float a00 = 0.f, a01 = 0.f, a02 = 0.f, a03 = 0.f;
    float a10 = 0.f, a11 = 0.f, a12 = 0.f, a13 = 0.f;
    const char* xbase = (const char*)xb;
    unsigned slb = (unsigned)sl << 3;               // byte offset within row

    unsigned c0 = 0, c1 = 0;
    while (c0 < mc0 || c1 < mc1) {
        int sv0 = (c0 + (unsigned)sl < mc0) ? sorted_src[st0 + c0 + sl] : N_NODES;
        int sv1 = (c1 + (unsigned)sl < mc1) ? sorted_src[st1 + c1 + sl] : N_NODES;
        unsigned rem0 = (c0 < mc0) ? ((mc0 - c0 > 32u) ? 32u : (mc0 - c0)) : 0u;
        unsigned rem1 = (c1 < mc1) ? ((mc1 - c1 > 32u) ? 32u : (mc1 - c1)) : 0u;
        unsigned rm = rem0 > rem1 ? rem0 : rem1;
        for (unsigned j = 0; j < rm; j += 4) {
            int s00 = __shfl(sv0, (int)j,     32);
            int s01 = __shfl(sv0, (int)j + 1, 32);
            int s02 = __shfl(sv0, (int)j + 2, 32);
            int s03 = __shfl(sv0, (int)j + 3, 32);
            int s10 = __shfl(sv1, (int)j,     32);
            int s11 = __shfl(sv1, (int)j + 1, 32);
            int s12 = __shfl(sv1, (int)j + 2, 32);
            int s13 = __shfl(sv1, (int)j + 3, 32);
            uint2 d00 = *(const uint2*)(xbase + ((((unsigned)s00) << 8) | slb));
            uint2 d01 = *(const uint2*)(xbase + ((((unsigned)s01) << 8) | slb));
            uint2 d02 = *(const uint2*)(xbase + ((((unsigned)s02) << 8) | slb));
            uint2 d03 = *(const uint2*)(xbase + ((((unsigned)s03) << 8) | slb));
            uint2 d10 = *(const uint2*)(xbase + ((((unsigned)s10) << 8) | slb));
            uint2 d11 = *(const uint2*)(xbase + ((((unsigned)s11) << 8) | slb));
            uint2 d12 = *(const uint2*)(xbase + ((((unsigned)s12) << 8) | slb));
            uint2 d13 = *(const uint2*)(xbase + ((((unsigned)s13) << 8) | slb));
            a00 += (bf_lo(d00.x) + bf_lo(d01.x)) + (bf_lo(d02.x) + bf_lo(d03.x));
            a01 += (bf_hi(d00.x) + bf_hi(d01.x)) + (bf_hi(d02.x) + bf_hi(d03.x));
            a02 += (bf_lo(d00.y) + bf_lo(d01.y)) + (bf_lo(d02.y) + bf_lo(d03.y));
            a03 += (bf_hi(d00.y) + bf_hi(d01.y)) + (bf_hi(d02.y) + bf_hi(d03.y));
            a10 += (bf_lo(d10.x) + bf_lo(d11.x)) + (bf_lo(d12.x) + bf_lo(d13.x));
            a11 += (bf_hi(d10.x) + bf_hi(d11.x)) + (bf_hi(d12.x) + bf_hi(d13.x));
            a12 += (bf_lo(d10.y) + bf_lo(d11.y)) + (bf_lo(d12.y) + bf_lo(d13.y));
            a13 += (bf_hi(d10.y) + bf_hi(d11.y)) + (bf_hi(d12.y) + bf_hi(d13.y));
        }
        c0 += rem0;
        c1 += rem1;
    }

    float inv0 = 1.0f / fmaxf((float)mc0, 1.0f);
    unsigned lo0 = (unsigned)f2bf(a00 * inv0) | ((unsigned)f2bf(a01 * inv0) << 16);
    unsigned hi0 = (unsigned)f2bf(a02 * inv0) | ((unsigned)f2bf(a03 * inv0) << 16);
    ((uint2*)(h + (size_t)g0 * DIM))[sl] = make_uint2(lo0, hi0);
    if (g1 < total) {
        float inv1 = 1.0f / fmaxf((float)mc1, 1.0f);
        unsigned lo1 = (unsigned)f2bf(a10 * inv1) | ((unsigned)f2bf(a11 * inv1) << 16);
        unsigned hi1 = (unsigned)f2bf(a12 * inv1) | ((unsigned)f2bf(a13 * inv1) << 16);
        ((uint2*)(h + (size_t)g1 * DIM))[sl] = make_uint2(lo1, hi1);
    }
}

// ---------------------------------------------------------------------------
// LDS-staged MFMA GEMM + optional fused bias+LN+ReLU. [R1 known-good form]
// ---------------------------------------------------------------------------
__global__ __launch_bounds__(512) void gemm_ln_kernel(const ushort_t* __restrict__ h,
                                                      int cr, int r0,
                                                      const ushort_t* __restrict__ xb,
                                                      const ushort_t* __restrict__ Bt,
                                                      int include_root,
                                                      const float* __restrict__ bias,
                                                      const float* __restrict__ gamma,
                                                      const float* __restrict__ beta,
                                                      float* __restrict__ out,
                                                      int accumulate, int do_ln) {
    __shared__ __align__(16) ushort_t As[128 * A_STRIDE];   // 34.8 KB
    __shared__ __align__(16) ushort_t Bs[128 * B_STRIDE];   // 34.8 KB

    int tid  = threadIdx.x;
    int w    = tid >> 6;          // 0..7
    int lane = tid & 63;
    int m    = lane & 15;
    int quad = lane >> 4;
    int n0   = blockIdx.x * 128;

    f32x4 acc[8];
#pragma unroll
    for (int j = 0; j < 8; ++j) acc[j] = (f32x4){0.f, 0.f, 0.f, 0.f};

    int nrel = cr + include_root;
    for (int rr = 0; rr < nrel; ++rr) {
        int rel = (rr < cr) ? (r0 + rr) : NREL;

        // ---- stage B: 2048 x 16B chunks, 4 per thread (batched) ----
#pragma unroll
        for (int p = 0; p < 4; ++p) {
            int c = tid + 512 * p;
            int row = c >> 4, ch = c & 15;
            uintx4 v = *(const uintx4*)(Bt + ((size_t)rel * DIM + row) * DIM + ch * 8);
            *(uintx4*)&Bs[row * B_STRIDE + ch * 8] = v;
        }
        // ---- stage A: 2048 x 16B chunks (128 rows), 4 per thread ----
#pragma unroll
        for (int p = 0; p < 4; ++p) {
            int c = tid + 512 * p;
            int row = c >> 4, ch = c & 15;
            uintx4 v = (uintx4){0u, 0u, 0u, 0u};
            int node = n0 + row;
            if (node < N_NODES) {
                const ushort_t* src = (rr < cr)
                    ? (h + ((size_t)node * cr + rr) * DIM)
                    : (xb + (size_t)node * DIM);
                v = *(const uintx4*)(src + ch * 8);
            }
            *(uintx4*)&As[row * A_STRIDE + ch * 8] = v;
        }
        __syncthreads();

        // ---- 32 MFMA per wave ----
#pragma unroll
        for (int t = 0; t < 4; ++t) {
            short8 af = *(const short8*)&As[(w * 16 + m) * A_STRIDE + t * 32 + quad * 8];
#pragma unroll
            for (int j = 0; j < 8; ++j) {
                short8 bf = *(const short8*)&Bs[(j * 16 + m) * B_STRIDE + t * 32 + quad * 8];
                acc[j] = __builtin_amdgcn_mfma_f32_16x16x32_bf16(af, bf, acc[j], 0, 0, 0);
            }
        }
        __syncthreads();
    }

    // ---- epilogue ----
    if (do_ln) {
        float bj[8], gj[8], btj[8];
#pragma unroll
        for (int j = 0; j < 8; ++j) {
            bj[j]  = bias[j * 16 + m];
            gj[j]  = gamma[j * 16 + m];
            btj[j] = beta[j * 16 + m];
        }
#pragma unroll
        for (int i = 0; i < 4; ++i) {
            float s = 0.f, sq = 0.f;
#pragma unroll
            for (int j = 0; j < 8; ++j) {
                float v = acc[j][i] + bj[j];
                s  += v;
                sq += v * v;
            }
#pragma unroll
            for (int off = 1; off < 16; off <<= 1) {
                s  += __shfl_xor(s, off, 64);
                sq += __shfl_xor(sq, off, 64);
            }
            float mean = s * (1.0f / DIM);
            float var  = sq * (1.0f / DIM) - mean * mean;
            float rstd = rsqrtf(var + LN_EPS);
            int node = n0 + w * 16 + quad * 4 + i;
            if (node < N_NODES) {
#pragma unroll
                for (int j = 0; j < 8; ++j) {
                    float v = acc[j][i] + bj[j];
                    v = (v - mean) * rstd * gj[j] + btj[j];
                    out[(size_t)node * DIM + j * 16 + m] = fmaxf(v, 0.f);
                }
            }
        }
    } else {
#pragma unroll
        for (int i = 0; i < 4; ++i) {
            int node = n0 + w * 16 + quad * 4 + i;
            if (node < N_NODES) {
#pragma unroll
                for (int j = 0; j < 8; ++j) {
                    size_t o = (size_t)node * DIM + j * 16 + m;
                    float v = acc[j][i];
                    if (accumulate) v += out[o];
                    out[o] = v;
                }
            }
        }
    }
}

// ---------------------------------------------------------------------------
// Standalone bias + LayerNorm + ReLU (fallback for chunked path).
// ---------------------------------------------------------------------------
__global__ __launch_bounds__(256) void ln_kernel(float* __restrict__ out,
                                                 const float* __restrict__ bias,
                                                 const float* __restrict__ gamma,
                                                 const float* __restrict__ beta) {
    int row  = blockIdx.x * 4 + (threadIdx.x >> 6);
    int lane = threadIdx.x & 63;
    if (row >= N_NODES) return;
    float2 v = *(float2*)(out + (size_t)row * DIM + lane * 2);
    float2 bi = *(const float2*)(bias + lane * 2);
    v.x += bi.x;
    v.y += bi.y;
    float s  = v.x + v.y;
    float sq = v.x * v.x + v.y * v.y;
#pragma unroll
    for (int off = 32; off > 0; off >>= 1) {
        s  += __shfl_xor(s, off, 64);
        sq += __shfl_xor(sq, off, 64);
    }
    float mean = s * (1.0f / DIM);
    float var  = sq * (1.0f / DIM) - mean * mean;
    float rstd = rsqrtf(var + LN_EPS);
    float2 g = *(const float2*)(gamma + lane * 2);
    float2 b = *(const float2*)(beta + lane * 2);
    v.x = fmaxf((v.x - mean) * rstd * g.x + b.x, 0.f);
    v.y = fmaxf((v.y - mean) * rstd * g.y + b.y, 0.f);
    *(float2*)(out + (size_t)row * DIM + lane * 2) = v;
}

// ---------------------------------------------------------------------------
extern "C" void kernel_launch(void* const* d_in, const int* in_sizes, int n_in,
                              void* d_out, int out_size, void* d_ws, size_t ws_size,
                              hipStream_t stream) {
    const float* x      = (const float*)d_in[0];
    const int*   ei     = (const int*)d_in[1];
    const int*   et     = (const int*)d_in[2];
    const float* W_rel  = (const float*)d_in[4];
    const float* W_root = (const float*)d_in[5];
    const float* bias   = (const float*)d_in[6];
    const float* gamma  = (const float*)d_in[7];
    const float* beta   = (const float*)d_in[8];
    float*       out    = (float*)d_out;

    // ---- workspace layout ----
    char* ws = (char*)d_ws;
    size_t off = 0;
    auto alloc = [&](size_t bytes) { char* p = ws + off; off = (off + bytes + 255) & ~(size_t)255; return p; };
    unsigned* block_hist = (unsigned*)alloc((size_t)NBIN * BH_STRIDE * 4);   // 2.5 MB
    unsigned* bin_tot    = (unsigned*)alloc((size_t)NBIN * 4);
    unsigned* bin_base   = (unsigned*)alloc((size_t)NBIN * 4);
    unsigned* rec        = (unsigned*)alloc((size_t)N_EDGES * 4);            // 6.4 MB
    uint2*    meta       = (uint2*)alloc((size_t)NKEYS * 8);                 // 3.2 MB
    int*      sorted_src = (int*)alloc((size_t)N_EDGES * 4);                 // 6.4 MB
    ushort_t* Bt         = (ushort_t*)alloc((size_t)9 * DIM * DIM * 2);
    ushort_t* xb         = (ushort_t*)alloc((size_t)(N_NODES + 1) * DIM * 2);  // +1 zero row
    size_t fixedOff = off;
    ushort_t* h = (ushort_t*)(ws + fixedOff);
    size_t availB = ws_size > fixedOff ? ws_size - fixedOff : 0;
    size_t perRel = (size_t)N_NODES * DIM * 2;   // 12.8 MB per relation (bf16)
    int chunkR = (int)(availB / perRel);
    if (chunkR > NREL) chunkR = NREL;
    if (chunkR < 1)    chunkR = 1;

    // ---- atomic-free two-level counting sort ----
    prep_kernel<<<PA_BLOCKS + XB_BLOCKS + BT_BLOCKS + 1, 256, 0, stream>>>(
        x, xb, W_rel, W_root, Bt, ei, et, block_hist);
    scanA2_kernel<<<NBIN, 256, 0, stream>>>(block_hist, bin_tot);
    scanA3_kernel<<<1, 512, 0, stream>>>(bin_tot, bin_base);
    passB_kernel<<<PA_BLOCKS, 256, 0, stream>>>(ei, et, block_hist, bin_base, rec);
    passC_kernel<<<NBIN, 256, 0, stream>>>(rec, bin_base, bin_tot, meta, sorted_src);

    int gemmGrid = (N_NODES + 127) / 128;   // 391 blocks

    if (chunkR >= NREL) {
        int nbuck = N_NODES * NREL;
        aggregate_kernel<<<(nbuck + 15) / 16, 256, 0, stream>>>(meta, sorted_src,
                                                                xb, h, 0, NREL);
        gemm_ln_kernel<<<gemmGrid, 512, 0, stream>>>(h, NREL, 0, xb, Bt, 1,
                                                     bias, gamma, beta, out, 0, 1);
    } else {
        for (int r0 = 0; r0 < NREL; r0 += chunkR) {
            int cr = (NREL - r0 < chunkR) ? (NREL - r0) : chunkR;
            int nbuck = N_NODES * cr;
            aggregate_kernel<<<(nbuck + 15) / 16, 256, 0, stream>>>(meta, sorted_src,
                                                                    xb, h, r0, cr);
            int include_root = (r0 + cr == NREL) ? 1 : 0;
            gemm_ln_kernel<<<gemmGrid, 512, 0, stream>>>(h, cr, r0, xb, Bt, include_root,
                                                         bias, gamma, beta, out,
                                                         r0 > 0 ? 1 : 0, 0);
        }
        ln_kernel<<<(N_NODES + 3) / 4, 256, 0, stream>>>(out, bias, gamma, beta);
    }
}

// Round 8
// 249.646 us; speedup vs baseline: 1.2651x; 1.0217x over previous
//
#include <hip/hip_runtime.h>
#include <hip/hip_bf16.h>
#include <cstdint>

#define N_NODES 50000
#define N_EDGES 1600000
#define DIM 128
#define NREL 8
#define LN_EPS 1e-5f

#define NKEYS (N_NODES * NREL)          // 400000
#define PA_BLOCKS ((N_EDGES + 1023) / 1024)   // 1563 (1024 edges/block)
#define NBIN ((NKEYS + 1023) / 1024)    // 391 coarse bins (key>>10)
#define BH_STRIDE 1600                  // padded blocks-per-bin row stride

#define A_STRIDE 136                    // ushorts per LDS A row (128 + 8 pad)
#define B_STRIDE 136                    // ushorts per LDS B row

#define XB_BLOCKS 6250                  // N_NODES*DIM/4 / 256
#define BT_BLOCKS 576                   // 9*128*128 / 256

typedef unsigned short ushort_t;
typedef short short8 __attribute__((ext_vector_type(8)));
typedef float f32x4 __attribute__((ext_vector_type(4)));
typedef unsigned uintx4 __attribute__((ext_vector_type(4)));

__device__ inline ushort_t f2bf(float f) {
    union { float f; unsigned u; } v; v.f = f;
    unsigned r = (v.u + 0x7FFFu + ((v.u >> 16) & 1u)) >> 16;
    return (ushort_t)r;
}
__device__ inline float bf_lo(unsigned u) {
    union { unsigned u; float f; } v; v.u = u << 16;
    return v.f;
}
__device__ inline float bf_hi(unsigned u) {
    union { unsigned u; float f; } v; v.u = u & 0xffff0000u;
    return v.f;
}

// ---------------------------------------------------------------------------
// Fused prep + Pass A (R17 win): per-1024-edge block LDS histogram over 391
// coarse bins (key>>10) -> block_hist[bin][block]; no global atomics.
// ---------------------------------------------------------------------------
__global__ __launch_bounds__(256) void prep_kernel(const float* __restrict__ x,
                                                   ushort_t* __restrict__ xb,
                                                   const float* __restrict__ W_rel,
                                                   const float* __restrict__ W_root,
                                                   ushort_t* __restrict__ Bt,
                                                   const int* __restrict__ ei,
                                                   const int* __restrict__ et,
                                                   unsigned* __restrict__ block_hist) {
    int b = blockIdx.x;
    int tid = threadIdx.x;
    if (b < PA_BLOCKS) {
        __shared__ unsigned hist[NBIN];
        for (int i = tid; i < NBIN; i += 256) hist[i] = 0u;
        __syncthreads();
        int e = b * 1024 + tid;
#pragma unroll
        for (int q = 0; q < 4; ++q) {
            int eq = e + q * 256;
            if (eq < N_EDGES) {
                int dst = ei[N_EDGES + eq];
                unsigned key = (unsigned)dst * NREL + (unsigned)et[eq];
                atomicAdd(&hist[key >> 10], 1u);
            }
        }
        __syncthreads();
        for (int i = tid; i < NBIN; i += 256)
            block_hist[(size_t)i * BH_STRIDE + b] = hist[i];
    } else if (b < PA_BLOCKS + XB_BLOCKS) {
        int i = (b - PA_BLOCKS) * 256 + tid;              // float4 index
        float4 v = ((const float4*)x)[i];
        unsigned lo = (unsigned)f2bf(v.x) | ((unsigned)f2bf(v.y) << 16);
        unsigned hi = (unsigned)f2bf(v.z) | ((unsigned)f2bf(v.w) << 16);
        ((uint2*)xb)[i] = make_uint2(lo, hi);
    } else if (b < PA_BLOCKS + XB_BLOCKS + BT_BLOCKS) {
        int i = (b - PA_BLOCKS - XB_BLOCKS) * 256 + tid;
        int r   = i >> 14;
        int rem = i & 16383;
        int n   = rem >> 7;
        int k   = rem & 127;
        const float* W = (r < NREL) ? (W_rel + (size_t)r * DIM * DIM) : W_root;
        Bt[i] = f2bf(W[(size_t)k * DIM + n]);
    } else {
        // zero row at node index N_NODES: 128 bf16 = 32 x uint2
        if (tid < 32)
            ((uint2*)(xb + (size_t)N_NODES * DIM))[tid] = make_uint2(0u, 0u);
    }
}

// ---------------------------------------------------------------------------
// Pass A2: per coarse bin, exclusive-scan its 1563 per-block counts in place;
// bin total to bin_tot. One block per bin.
// ---------------------------------------------------------------------------
__global__ __launch_bounds__(256) void scanA2_kernel(unsigned* __restrict__ bh,
                                                     unsigned* __restrict__ bin_tot) {
    __shared__ unsigned lds[256];
    int k = blockIdx.x;
    int tid = threadIdx.x;
    unsigned* row = bh + (size_t)k * BH_STRIDE;
    int base = tid * 7;                               // 7*256 = 1792 >= 1563
    unsigned v[7];
    unsigned s = 0;
#pragma unroll
    for (int j = 0; j < 7; ++j) {
        int i = base + j;
        v[j] = (i < PA_BLOCKS) ? row[i] : 0u;
        s += v[j];
    }
    lds[tid] = s;
    __syncthreads();
    for (int off = 1; off < 256; off <<= 1) {
        unsigned a = (tid >= off) ? lds[tid - off] : 0u;
        __syncthreads();
        lds[tid] += a;
        __syncthreads();
    }
    unsigned ex = lds[tid] - s;
#pragma unroll
    for (int j = 0; j < 7; ++j) {
        int i = base + j;
        if (i < PA_BLOCKS) {
            unsigned t = v[j];
            row[i] = ex;
            ex += t;
        }
    }
    if (tid == 255) bin_tot[k] = lds[255];
}

// ---------------------------------------------------------------------------
// Pass A3: exclusive scan of the 391 bin totals -> absolute bin bases.
// ---------------------------------------------------------------------------
__global__ __launch_bounds__(512) void scanA3_kernel(const unsigned* __restrict__ bin_tot,
                                                     unsigned* __restrict__ bin_base) {
    __shared__ unsigned lds[512];
    int tid = threadIdx.x;
    unsigned v = (tid < NBIN) ? bin_tot[tid] : 0u;
    lds[tid] = v;
    __syncthreads();
    for (int off = 1; off < 512; off <<= 1) {
        unsigned a = (tid >= off) ? lds[tid - off] : 0u;
        __syncthreads();
        lds[tid] += a;
        __syncthreads();
    }
    if (tid < NBIN) bin_base[tid] = lds[tid] - v;
}

// ---------------------------------------------------------------------------
// Pass B: scatter edges into coarse-bin-contiguous records. Per-block LDS
// cursors; local rank via LDS atomic. Record packs (src<<10)|(key&1023).
// ---------------------------------------------------------------------------
__global__ __launch_bounds__(256) void passB_kernel(const int* __restrict__ ei,
                                                    const int* __restrict__ et,
                                                    const unsigned* __restrict__ bh,
                                                    const unsigned* __restrict__ bin_base,
                                                    unsigned* __restrict__ rec) {
    __shared__ unsigned col[NBIN];
    __shared__ unsigned rk[NBIN];
    int b = blockIdx.x;
    int tid = threadIdx.x;
    for (int i = tid; i < NBIN; i += 256) {
        col[i] = bin_base[i] + bh[(size_t)i * BH_STRIDE + b];
        rk[i]  = 0u;
    }
    __syncthreads();
    int e = b * 1024 + tid;
#pragma unroll
    for (int q = 0; q < 4; ++q) {
        int eq = e + q * 256;
        if (eq < N_EDGES) {
            int src = ei[eq];
            int dst = ei[N_EDGES + eq];
            unsigned key = (unsigned)dst * NREL + (unsigned)et[eq];
            unsigned bin = key >> 10;
            unsigned r = atomicAdd(&rk[bin], 1u);
            rec[col[bin] + r] = ((unsigned)src << 10) | (key & 1023u);
        }
    }
}

// ---------------------------------------------------------------------------
// Pass C: per coarse bin fine counting sort (1024 keys). LDS count -> LDS
// scan -> meta (ABSOLUTE starts) -> LDS-cursor scatter of sorted_src.
// ---------------------------------------------------------------------------
__global__ __launch_bounds__(256) void passC_kernel(const unsigned* __restrict__ rec,
                                                    const unsigned* __restrict__ bin_base,
                                                    const unsigned* __restrict__ bin_tot,
                                                    uint2* __restrict__ meta,
                                                    int* __restrict__ sorted_src) {
    __shared__ unsigned cnt[1024];     // counts, then cursors
    __shared__ unsigned lds[256];
    int k = blockIdx.x;
    int tid = threadIdx.x;
    unsigned base = bin_base[k];
    unsigned tot  = bin_tot[k];
    for (int i = tid; i < 1024; i += 256) cnt[i] = 0u;
    __syncthreads();
    for (unsigned i = tid; i < tot; i += 256) {
        unsigned r = rec[base + i];
        atomicAdd(&cnt[r & 1023u], 1u);
    }
    __syncthreads();
    unsigned v[4], incl[4], s = 0;
#pragma unroll
    for (int j = 0; j < 4; ++j) {
        v[j] = cnt[tid * 4 + j];
        s += v[j];
        incl[j] = s;
    }
    lds[tid] = s;
    __syncthreads();
    for (int off = 1; off < 256; off <<= 1) {
        unsigned a = (tid >= off) ? lds[tid - off] : 0u;
        __syncthreads();
        lds[tid] += a;
        __syncthreads();
    }
    unsigned bs = lds[tid] - s;
    unsigned key0 = (unsigned)k * 1024 + tid * 4;
#pragma unroll
    for (int j = 0; j < 4; ++j) {
        unsigned ex = bs + incl[j] - v[j];
        if (key0 + j < NKEYS) meta[key0 + j] = make_uint2(base + ex, v[j]);
    }
    __syncthreads();
#pragma unroll
    for (int j = 0; j < 4; ++j) cnt[tid * 4 + j] = bs + incl[j] - v[j];   // cursors
    __syncthreads();
    for (unsigned i = tid; i < tot; i += 256) {
        unsigned r = rec[base + i];
        unsigned q = r & 1023u;
        unsigned p = atomicAdd(&cnt[q], 1u);
        sorted_src[base + p] = (int)(r >> 10);
    }
}

// ---------------------------------------------------------------------------
// R15 aggregate (2-chain, ~69 us, occ ~71%); meta.x ABSOLUTE.
// ---------------------------------------------------------------------------
__global__ __launch_bounds__(256) void aggregate_kernel(const uint2* __restrict__ meta,
                                                        const int* __restrict__ sorted_src,
                                                        const ushort_t* __restrict__ xb,
                                                        ushort_t* __restrict__ h,
                                                        int r0, int cr) {
    int hw = threadIdx.x >> 5;                      // half-wave id 0..7
    int sl = threadIdx.x & 31;                      // lane covers 4 feats
    int g0 = blockIdx.x * 16 + hw * 2;              // first bucket
    int g1 = g0 + 1;
    int total = N_NODES * cr;
    if (g0 >= total) return;

    unsigned st0, mc0, st1 = 0u, mc1 = 0u;
    if (cr == NREL) {
        uint4 mm = *(const uint4*)&meta[(unsigned)g0];
        st0 = mm.x; mc0 = mm.y;
        st1 = mm.z; mc1 = mm.w;
    } else {
        int n0 = g0 / cr, rl0 = g0 - n0 * cr;
        unsigned key0 = (unsigned)n0 * NREL + (unsigned)(r0 + rl0);
        uint2 md0 = meta[key0];
        st0 = md0.x; mc0 = md0.y;
        if (g1 < total) {
            int n1 = g1 / cr, rl1 = g1 - n1 * cr;
            unsigned key1 = (unsigned)n1 * NREL + (unsigned)(r0 + rl1);
            uint2 md1 = meta[key1];
            st1 = md1.x; mc1 = md1.y;
        }
    }

    float a00 = 0.f, a01 = 0.f, a02 = 0.f, a03 = 0.f;
    float a10 = 0.f, a11 = 0.f, a12 = 0.f, a13 = 0.f;
    const char* xbase = (const char*)xb;
    unsigned slb = (unsigned)sl << 3;               // byte offset within row

    unsigned c0 = 0, c1 = 0;
    while (c0 < mc0 || c1 < mc1) {
        int sv0 = (c0 + (unsigned)sl < mc0) ? sorted_src[st0 + c0 + sl] : N_NODES;
        int sv1 = (c1 + (unsigned)sl < mc1) ? sorted_src[st1 + c1 + sl] : N_NODES;
        unsigned rem0 = (c0 < mc0) ? ((mc0 - c0 > 32u) ? 32u : (mc0 - c0)) : 0u;
        unsigned rem1 = (c1 < mc1) ? ((mc1 - c1 > 32u) ? 32u : (mc1 - c1)) : 0u;
        unsigned rm = rem0 > rem1 ? rem0 : rem1;
        for (unsigned j = 0; j < rm; j += 4) {
            int s00 = __shfl(sv0, (int)j,     32);
            int s01 = __shfl(sv0, (int)j + 1, 32);
            int s02 = __shfl(sv0, (int)j + 2, 32);
            int s03 = __shfl(sv0, (int)j + 3, 32);
            int s10 = __shfl(sv1, (int)j,     32);
            int s11 = __shfl(sv1, (int)j + 1, 32);
            int s12 = __shfl(sv1, (int)j + 2, 32);
            int s13 = __shfl(sv1, (int)j + 3, 32);
            uint2 d00 = *(const uint2*)(xbase + ((((unsigned)s00) << 8) | slb));
            uint2 d01 = *(const uint2*)(xbase + ((((unsigned)s01) << 8) | slb));
            uint2 d02 = *(const uint2*)(xbase + ((((unsigned)s02) << 8) | slb));
            uint2 d03 = *(const uint2*)(xbase + ((((unsigned)s03) << 8) | slb));
            uint2 d10 = *(const uint2*)(xbase + ((((unsigned)s10) << 8) | slb));
            uint2 d11 = *(const uint2*)(xbase + ((((unsigned)s11) << 8) | slb));
            uint2 d12 = *(const uint2*)(xbase + ((((unsigned)s12) << 8) | slb));
            uint2 d13 = *(const uint2*)(xbase + ((((unsigned)s13) << 8) | slb));
            a00 += (bf_lo(d00.x) + bf_lo(d01.x)) + (bf_lo(d02.x) + bf_lo(d03.x));
            a01 += (bf_hi(d00.x) + bf_hi(d01.x)) + (bf_hi(d02.x) + bf_hi(d03.x));
            a02 += (bf_lo(d00.y) + bf_lo(d01.y)) + (bf_lo(d02.y) + bf_lo(d03.y));
            a03 += (bf_hi(d00.y) + bf_hi(d01.y)) + (bf_hi(d02.y) + bf_hi(d03.y));
            a10 += (bf_lo(d10.x) + bf_lo(d11.x)) + (bf_lo(d12.x) + bf_lo(d13.x));
            a11 += (bf_hi(d10.x) + bf_hi(d11.x)) + (bf_hi(d12.x) + bf_hi(d13.x));
            a12 += (bf_lo(d10.y) + bf_lo(d11.y)) + (bf_lo(d12.y) + bf_lo(d13.y));
            a13 += (bf_hi(d10.y) + bf_hi(d11.y)) + (bf_hi(d12.y) + bf_hi(d13.y));
        }
        c0 += rem0;
        c1 += rem1;
    }

    float inv0 = 1.0f / fmaxf((float)mc0, 1.0f);
    unsigned lo0 = (unsigned)f2bf(a00 * inv0) | ((unsigned)f2bf(a01 * inv0) << 16);
    unsigned hi0 = (unsigned)f2bf(a02 * inv0) | ((unsigned)f2bf(a03 * inv0) << 16);
    ((uint2*)(h + (size_t)g0 * DIM))[sl] = make_uint2(lo0, hi0);
    if (g1 < total) {
        float inv1 = 1.0f / fmaxf((float)mc1, 1.0f);
        unsigned lo1 = (unsigned)f2bf(a10 * inv1) | ((unsigned)f2bf(a11 * inv1) << 16);
        unsigned hi1 = (unsigned)f2bf(a12 * inv1) | ((unsigned)f2bf(a13 * inv1) << 16);
        ((uint2*)(h + (size_t)g1 * DIM))[sl] = make_uint2(lo1, hi1);
    }
}

// ---------------------------------------------------------------------------
// LDS-staged MFMA GEMM + fused bias+LN+ReLU.
// R18: register-prefetch pipeline across the rel loop (T14 issue-early/
// write-late). The old form paid full HBM latency per rel inside a lockstep
// barrier section (391 blocks / 256 CU = ~1.5 blocks/CU -> no TLP to hide
// it). Now rel rr+1's 8 dwordx4 loads (A from h/xb, B from Bt) are issued
// BEFORE rel rr's MFMA phase; regs are written to LDS after the post-MFMA
// barrier. +32 VGPR, same LDS (69.6 KB, 2 blocks/CU).
// ---------------------------------------------------------------------------
__global__ __launch_bounds__(512) void gemm_ln_kernel(const ushort_t* __restrict__ h,
                                                      int cr, int r0,
                                                      const ushort_t* __restrict__ xb,
                                                      const ushort_t* __restrict__ Bt,
                                                      int include_root,
                                                      const float* __restrict__ bias,
                                                      const float* __restrict__ gamma,
                                                      const float* __restrict__ beta,
                                                      float* __restrict__ out,
                                                      int accumulate, int do_ln) {
    __shared__ __align__(16) ushort_t As[128 * A_STRIDE];   // 34.8 KB
    __shared__ __align__(16) ushort_t Bs[128 * B_STRIDE];   // 34.8 KB

    int tid  = threadIdx.x;
    int w    = tid >> 6;          // 0..7
    int lane = tid & 63;
    int m    = lane & 15;
    int quad = lane >> 4;
    int n0   = blockIdx.x * 128;

    f32x4 acc[8];
#pragma unroll
    for (int j = 0; j < 8; ++j) acc[j] = (f32x4){0.f, 0.f, 0.f, 0.f};

    int nrel = cr + include_root;

    // per-thread staging chunk coords (4 chunks, 16B each)
    int rowc[4], chc[4];
#pragma unroll
    for (int p = 0; p < 4; ++p) {
        int c = tid + 512 * p;
        rowc[p] = c >> 4;
        chc[p]  = c & 15;
    }

    uintx4 ra[4], rb[4];
    auto loadRel = [&](int rr) {
        int rel = (rr < cr) ? (r0 + rr) : NREL;
#pragma unroll
        for (int p = 0; p < 4; ++p) {
            rb[p] = *(const uintx4*)(Bt + ((size_t)rel * DIM + rowc[p]) * DIM + chc[p] * 8);
            uintx4 v = (uintx4){0u, 0u, 0u, 0u};
            int node = n0 + rowc[p];
            if (node < N_NODES) {
                const ushort_t* src = (rr < cr)
                    ? (h + ((size_t)node * cr + rr) * DIM)
                    : (xb + (size_t)node * DIM);
                v = *(const uintx4*)(src + chc[p] * 8);
            }
            ra[p] = v;
        }
    };
    auto writeLDS = [&]() {
#pragma unroll
        for (int p = 0; p < 4; ++p) {
            *(uintx4*)&Bs[rowc[p] * B_STRIDE + chc[p] * 8] = rb[p];
            *(uintx4*)&As[rowc[p] * A_STRIDE + chc[p] * 8] = ra[p];
        }
    };

    // prologue: stage rel 0
    loadRel(0);
    writeLDS();
    __syncthreads();

    for (int rr = 0; rr < nrel; ++rr) {
        // issue next rel's loads BEFORE the MFMA phase (latency hides under MFMA)
        if (rr + 1 < nrel) loadRel(rr + 1);

        // ---- 32 MFMA per wave ----
#pragma unroll
        for (int t = 0; t < 4; ++t) {
            short8 af = *(const short8*)&As[(w * 16 + m) * A_STRIDE + t * 32 + quad * 8];
#pragma unroll
            for (int j = 0; j < 8; ++j) {
                short8 bf = *(const short8*)&Bs[(j * 16 + m) * B_STRIDE + t * 32 + quad * 8];
                acc[j] = __builtin_amdgcn_mfma_f32_16x16x32_bf16(af, bf, acc[j], 0, 0, 0);
            }
        }
        __syncthreads();                 // all LDS reads of this rel done
        if (rr + 1 < nrel) {
            writeLDS();                  // regs (load-complete by waitcnt) -> LDS
            __syncthreads();             // LDS ready for next rel
        }
    }

    // ---- epilogue ----
    if (do_ln) {
        float bj[8], gj[8], btj[8];
#pragma unroll
        for (int j = 0; j < 8; ++j) {
            bj[j]  = bias[j * 16 + m];
            gj[j]  = gamma[j * 16 + m];
            btj[j] = beta[j * 16 + m];
        }
#pragma unroll
        for (int i = 0; i < 4; ++i) {
            float s = 0.f, sq = 0.f;
#pragma unroll
            for (int j = 0; j < 8; ++j) {
                float v = acc[j][i] + bj[j];
                s  += v;
                sq += v * v;
            }
#pragma unroll
            for (int off = 1; off < 16; off <<= 1) {
                s  += __shfl_xor(s, off, 64);
                sq += __shfl_xor(sq, off, 64);
            }
            float mean = s * (1.0f / DIM);
            float var  = sq * (1.0f / DIM) - mean * mean;
            float rstd = rsqrtf(var + LN_EPS);
            int node = n0 + w * 16 + quad * 4 + i;
            if (node < N_NODES) {
#pragma unroll
                for (int j = 0; j < 8; ++j) {
                    float v = acc[j][i] + bj[j];
                    v = (v - mean) * rstd * gj[j] + btj[j];
                    out[(size_t)node * DIM + j * 16 + m] = fmaxf(v, 0.f);
                }
            }
        }
    } else {
#pragma unroll
        for (int i = 0; i < 4; ++i) {
            int node = n0 + w * 16 + quad * 4 + i;
            if (node < N_NODES) {
#pragma unroll
                for (int j = 0; j < 8; ++j) {
                    size_t o = (size_t)node * DIM + j * 16 + m;
                    float v = acc[j][i];
                    if (accumulate) v += out[o];
                    out[o] = v;
                }
            }
        }
    }
}

// ---------------------------------------------------------------------------
// Standalone bias + LayerNorm + ReLU (fallback for chunked path).
// ---------------------------------------------------------------------------
__global__ __launch_bounds__(256) void ln_kernel(float* __restrict__ out,
                                                 const float* __restrict__ bias,
                                                 const float* __restrict__ gamma,
                                                 const float* __restrict__ beta) {
    int row  = blockIdx.x * 4 + (threadIdx.x >> 6);
    int lane = threadIdx.x & 63;
    if (row >= N_NODES) return;
    float2 v = *(float2*)(out + (size_t)row * DIM + lane * 2);
    float2 bi = *(const float2*)(bias + lane * 2);
    v.x += bi.x;
    v.y += bi.y;
    float s  = v.x + v.y;
    float sq = v.x * v.x + v.y * v.y;
#pragma unroll
    for (int off = 32; off > 0; off >>= 1) {
        s  += __shfl_xor(s, off, 64);
        sq += __shfl_xor(sq, off, 64);
    }
    float mean = s * (1.0f / DIM);
    float var  = sq * (1.0f / DIM) - mean * mean;
    float rstd = rsqrtf(var + LN_EPS);
    float2 g = *(const float2*)(gamma + lane * 2);
    float2 b = *(const float2*)(beta + lane * 2);
    v.x = fmaxf((v.x - mean) * rstd * g.x + b.x, 0.f);
    v.y = fmaxf((v.y - mean) * rstd * g.y + b.y, 0.f);
    *(float2*)(out + (size_t)row * DIM + lane * 2) = v;
}

// ---------------------------------------------------------------------------
extern "C" void kernel_launch(void* const* d_in, const int* in_sizes, int n_in,
                              void* d_out, int out_size, void* d_ws, size_t ws_size,
                              hipStream_t stream) {
    const float* x      = (const float*)d_in[0];
    const int*   ei     = (const int*)d_in[1];
    const int*   et     = (const int*)d_in[2];
    const float* W_rel  = (const float*)d_in[4];
    const float* W_root = (const float*)d_in[5];
    const float* bias   = (const float*)d_in[6];
    const float* gamma  = (const float*)d_in[7];
    const float* beta   = (const float*)d_in[8];
    float*       out    = (float*)d_out;

    // ---- workspace layout ----
    char* ws = (char*)d_ws;
    size_t off = 0;
    auto alloc = [&](size_t bytes) { char* p = ws + off; off = (off + bytes + 255) & ~(size_t)255; return p; };
    unsigned* block_hist = (unsigned*)alloc((size_t)NBIN * BH_STRIDE * 4);   // 2.5 MB
    unsigned* bin_tot    = (unsigned*)alloc((size_t)NBIN * 4);
    unsigned* bin_base   = (unsigned*)alloc((size_t)NBIN * 4);
    unsigned* rec        = (unsigned*)alloc((size_t)N_EDGES * 4);            // 6.4 MB
    uint2*    meta       = (uint2*)alloc((size_t)NKEYS * 8);                 // 3.2 MB
    int*      sorted_src = (int*)alloc((size_t)N_EDGES * 4);                 // 6.4 MB
    ushort_t* Bt         = (ushort_t*)alloc((size_t)9 * DIM * DIM * 2);
    ushort_t* xb         = (ushort_t*)alloc((size_t)(N_NODES + 1) * DIM * 2);  // +1 zero row
    size_t fixedOff = off;
    ushort_t* h = (ushort_t*)(ws + fixedOff);
    size_t availB = ws_size > fixedOff ? ws_size - fixedOff : 0;
    size_t perRel = (size_t)N_NODES * DIM * 2;   // 12.8 MB per relation (bf16)
    int chunkR = (int)(availB / perRel);
    if (chunkR > NREL) chunkR = NREL;
    if (chunkR < 1)    chunkR = 1;

    // ---- atomic-free two-level counting sort ----
    prep_kernel<<<PA_BLOCKS + XB_BLOCKS + BT_BLOCKS + 1, 256, 0, stream>>>(
        x, xb, W_rel, W_root, Bt, ei, et, block_hist);
    scanA2_kernel<<<NBIN, 256, 0, stream>>>(block_hist, bin_tot);
    scanA3_kernel<<<1, 512, 0, stream>>>(bin_tot, bin_base);
    passB_kernel<<<PA_BLOCKS, 256, 0, stream>>>(ei, et, block_hist, bin_base, rec);
    passC_kernel<<<NBIN, 256, 0, stream>>>(rec, bin_base, bin_tot, meta, sorted_src);

    int gemmGrid = (N_NODES + 127) / 128;   // 391 blocks

    if (chunkR >= NREL) {
        int nbuck = N_NODES * NREL;
        aggregate_kernel<<<(nbuck + 15) / 16, 256, 0, stream>>>(meta, sorted_src,
                                                                xb, h, 0, NREL);
        gemm_ln_kernel<<<gemmGrid, 512, 0, stream>>>(h, NREL, 0, xb, Bt, 1,
                                                     bias, gamma, beta, out, 0, 1);
    } else {
        for (int r0 = 0; r0 < NREL; r0 += chunkR) {
            int cr = (NREL - r0 < chunkR) ? (NREL - r0) : chunkR;
            int nbuck = N_NODES * cr;
            aggregate_kernel<<<(nbuck + 15) / 16, 256, 0, stream>>>(meta, sorted_src,
                                                                    xb, h, r0, cr);
            int include_root = (r0 + cr == NREL) ? 1 : 0;
            gemm_ln_kernel<<<gemmGrid, 512, 0, stream>>>(h, cr, r0, xb, Bt, include_root,
                                                         bias, gamma, beta, out,
                                                         r0 > 0 ? 1 : 0, 0);
        }
        ln_kernel<<<(N_NODES + 3) / 4, 256, 0, stream>>>(out, bias, gamma, beta);
    }
}